// Round 13
// baseline (103.579 us; speedup 1.0000x reference)
//
#include <hip/hip_runtime.h>
#include <hip/hip_fp16.h>

#define KDIM 1024
#define DDIM 64
#define SPAT 32768
#define NVEC 65536
#define DSP  (DDIM * SPAT)          // 2097152
#define MARGIN_ACC 0.25f            // acc-space (= 512*dist); error bound ~0.12 worst case
#define ZPAD 65                     // odd stride -> conflict-free fixed-d/different-row reads
#define QCAP 512

typedef _Float16 half8 __attribute__((ext_vector_type(8)));
typedef float floatx4 __attribute__((ext_vector_type(4)));

__device__ __forceinline__ float opaque(float x) { asm volatile("" : "+v"(x)); return x; }

// sortable-uint transform for signed floats (monotone increasing)
__device__ __forceinline__ unsigned int f2s(float x) {
    unsigned int u = __float_as_uint(x);
    return u ^ ((u >> 31) ? 0xffffffffu : 0x80000000u);
}
__device__ __forceinline__ float s2f(unsigned int u) {
    unsigned int v = u ^ ((u & 0x80000000u) ? 0x80000000u : 0xffffffffu);
    return __uint_as_float(v);
}

// Bitwise replica of np.add.reduce pairwise base case over fl(x[d]^2), d=0..63 (R3-proven)
__device__ __forceinline__ float np_sumsq64(const float* x) {
    float r8[8];
#pragma unroll
    for (int j = 0; j < 8; ++j) r8[j] = opaque(x[1 + j] * x[1 + j]);
#pragma unroll
    for (int i = 8; i < 56; i += 8) {
#pragma unroll
        for (int j = 0; j < 8; ++j) r8[j] += opaque(x[1 + i + j] * x[1 + i + j]);
    }
    float res = ((r8[0] + r8[1]) + (r8[2] + r8[3])) + ((r8[4] + r8[5]) + (r8[6] + r8[7]));
#pragma unroll
    for (int m = 57; m < 64; ++m) res += opaque(x[m] * x[m]);
    return opaque(x[0] * x[0]) + res;
}

// Bit-exact numpy-f32 distance, packed (distbits<<32)|k. fl(2e)*z == fma(2e, z) exact 2x.
__device__ __forceinline__ unsigned long long exact_score(
    const float* zr, float snr, const float* __restrict__ emb,
    const float* __restrict__ h_, int k)
{
    const float* ep = emb + (size_t)k * DDIM;
    float acc = 0.f;
#pragma unroll
    for (int d = 0; d < DDIM; ++d)
        acc = fmaf(2.0f * ep[d], zr[d], acc);  // sgemm: sequential f32 FMA from 0, ascending d
    float tt   = snr + h_[k];                  // fl(sn + h)
    float dist = tt - acc;                     // fl(t - 2 z.e)
    return ((unsigned long long)__float_as_uint(dist) << 32) | (unsigned int)k;
}

// K1 (64 blocks x 16 k-rows): eh = fp16(e*1024); h = np-f32 ||e||^2; hneg = -512*h; loss = 0
__global__ void vq_prep_e(const float* __restrict__ emb, float* __restrict__ h,
                          float* __restrict__ hneg, __half* __restrict__ eh,
                          float* __restrict__ loss) {
    const int tid = threadIdx.x;
    const int kbase = blockIdx.x * 16;
#pragma unroll
    for (int i = 0; i < 4; ++i) {
        int g = i * 256 + tid;
        float v = emb[(size_t)kbase * DDIM + g];
        eh[(size_t)kbase * DDIM + g] = (__half)(_Float16)(v * 1024.0f);
    }
    if (tid < 16) {
        float s = np_sumsq64(emb + (size_t)(kbase + tid) * DDIM);
        h[kbase + tid]    = s;
        hneg[kbase + tid] = -512.0f * s;
    }
    if (blockIdx.x == 0 && tid == 0) *loss = 0.f;
}

// K2: two-pass MFMA (C-folded h) -> candidate queue -> bit-exact rescore -> epilogue
__global__ __launch_bounds__(256, 4) void vq_mfma_kernel(
    const float* __restrict__ z, const float* __restrict__ emb,
    const __half* __restrict__ eh_, const float* __restrict__ h_,
    const float* __restrict__ hneg_, float* __restrict__ out,
    float* __restrict__ loss, float* __restrict__ idxf)
{
    __shared__ float zrow[64 * ZPAD];            // 16.6 KB
    __shared__ float lds_sn[64];
    __shared__ unsigned int m1bits[64];          // sortable-uint row max (acc space)
    __shared__ int qcnt;
    __shared__ unsigned short qk[QCAP];
    __shared__ unsigned char  qn[QCAP];
    __shared__ unsigned long long rbest[64];

    const int tid = threadIdx.x, l = tid & 63, w = tid >> 6;
    const int nbase = blockIdx.x * 64;
    const int b = nbase >> 15, s0 = nbase & (SPAT - 1);
    const int col16 = l & 15, g16 = l >> 4;
    const float* zbase = z + (size_t)b * DSP + s0;

    if (tid == 0) qcnt = 0;
    if (tid < 64) { rbest[tid] = ~0ull; m1bits[tid] = 0u; }

    // stage 64 z-rows: wave w loads planes [w*16, w*16+16), lane = row (coalesced 256B)
    {
        const int dbase = w * 16;
#pragma unroll
        for (int j = 0; j < 16; ++j)
            zrow[l * ZPAD + dbase + j] = zbase[(size_t)(dbase + j) * SPAT + l];
    }
    __syncthreads();

    // parallel sumsq: wave w computes rows [w*16, w*16+16) via its lanes 0..15
    if (l < 16) lds_sn[w * 16 + l] = np_sumsq64(&zrow[(w * 16 + l) * ZPAD]);

    // resident Z hi fragments
    half8 zf[4][2];
#pragma unroll
    for (int nc = 0; nc < 4; ++nc) {
        const int r = nc * 16 + col16;
#pragma unroll
        for (int kp = 0; kp < 2; ++kp) {
            const int d0 = g16 * 8 + kp * 32;
            half8 vh;
#pragma unroll
            for (int u = 0; u < 8; ++u)
                vh[u] = (_Float16)zrow[r * ZPAD + d0 + u];
            zf[nc][kp] = vh;
        }
    }

    const int myk0 = w * 256;
    half8 f0[3], f1[3]; floatx4 hc[3];
    // acc = -512*dist exactly: C-init = -512*h, and 2^-9 * (1024*dot) * 512 folds to dot term
#define LOADT(slot, t) { \
        const size_t o_ = (size_t)(myk0 + (t) * 16 + col16) * DDIM + g16 * 8; \
        f0[slot] = *(const half8*)(eh_ + o_); \
        f1[slot] = *(const half8*)(eh_ + o_ + 32); \
        hc[slot] = *(const floatx4*)(hneg_ + myk0 + (t) * 16 + g16 * 4); }

    // ---- pass 1: approx row MAX of acc (= min dist), 2-deep prefetch ----
    float m1[4];
#pragma unroll
    for (int nc = 0; nc < 4; ++nc) m1[nc] = -3.0e38f;
    LOADT(0, 0) LOADT(1, 1)
#pragma unroll
    for (int t = 0; t < 16; ++t) {
        const int cs = t % 3;
        if (t < 14) LOADT((t + 2) % 3, t + 2)
#pragma unroll
        for (int nc = 0; nc < 4; ++nc) {
            floatx4 acc = __builtin_amdgcn_mfma_f32_16x16x32_f16(f0[cs], zf[nc][0], hc[cs], 0, 0, 0);
            acc = __builtin_amdgcn_mfma_f32_16x16x32_f16(f1[cs], zf[nc][1], acc, 0, 0, 0);
            m1[nc] = fmaxf(m1[nc], fmaxf(fmaxf(acc[0], acc[1]), fmaxf(acc[2], acc[3])));
        }
    }
#pragma unroll
    for (int nc = 0; nc < 4; ++nc)
        atomicMax(&m1bits[nc * 16 + col16], f2s(m1[nc]));
    __syncthreads();

    float thr[4];
#pragma unroll
    for (int nc = 0; nc < 4; ++nc) thr[nc] = s2f(m1bits[nc * 16 + col16]) - MARGIN_ACC;

    // ---- pass 2: re-scan, push candidates with acc >= rowmax - MARGIN_ACC ----
    LOADT(0, 0) LOADT(1, 1)
#pragma unroll
    for (int t = 0; t < 16; ++t) {
        const int cs = t % 3;
        if (t < 14) LOADT((t + 2) % 3, t + 2)
        const int rbase = myk0 + t * 16 + g16 * 4;
#pragma unroll
        for (int nc = 0; nc < 4; ++nc) {
            floatx4 acc = __builtin_amdgcn_mfma_f32_16x16x32_f16(f0[cs], zf[nc][0], hc[cs], 0, 0, 0);
            acc = __builtin_amdgcn_mfma_f32_16x16x32_f16(f1[cs], zf[nc][1], acc, 0, 0, 0);
#pragma unroll
            for (int j = 0; j < 4; ++j) {
                if (acc[j] >= thr[nc]) {
                    int p = atomicAdd(&qcnt, 1);
                    if (p < QCAP) {
                        qk[p] = (unsigned short)(rbase + j);
                        qn[p] = (unsigned char)(nc * 16 + col16);
                    }
                }
            }
        }
    }
#undef LOADT
    __syncthreads();

    // ---- phase 3: bit-exact numpy-f32 rescore of candidates, atomicMin per row ----
    const int qlen = min(qcnt, QCAP);
    for (int i = tid; i < qlen; i += 256) {
        const int r = qn[i];
        atomicMin(&rbest[r], exact_score(&zrow[r * ZPAD], lds_sn[r], emb, h_, qk[i]));
    }
    __syncthreads();

    if (qcnt > QCAP) {   // cold correctness fallback: full exact scan
        const int row = tid & 63, kq = tid >> 6;
        for (int k = kq * 256; k < kq * 256 + 256; ++k)
            atomicMin(&rbest[row], exact_score(&zrow[row * ZPAD], lds_sn[row], emb, h_, k));
        __syncthreads();
    }

    // ---- epilogue: idx, z_q gather (all 4 waves, coalesced 256B stores), loss ----
    if (tid < 64) idxf[nbase + tid] = (float)(unsigned int)(rbest[tid] & 0xffffffffu);
    {
        const int I1 = (int)(rbest[l] & 0xffffffffu);   // this lane's row
        const int dbase = w * 16;
        float* opb = out + (size_t)b * DSP + s0;
        float lsum = 0.f;
#pragma unroll
        for (int j = 0; j < 16; ++j) {
            const int d = dbase + j;
            float qv = emb[(size_t)I1 * DDIM + d];
            opb[(size_t)d * SPAT + l] = qv;
            float df = qv - zrow[l * ZPAD + d];
            lsum = fmaf(df, df, lsum);
        }
#pragma unroll
        for (int off = 32; off > 0; off >>= 1)
            lsum += __shfl_down(lsum, off, 64);
        if (l == 0)
            atomicAdd(loss, lsum * (1.25f / 4194304.0f));  // (beta+1)*mean
    }
}

extern "C" void kernel_launch(void* const* d_in, const int* in_sizes, int n_in,
                              void* d_out, int out_size, void* d_ws, size_t ws_size,
                              hipStream_t stream) {
    const float* z   = (const float*)d_in[0];   // [2, 64, 32, 32, 32]
    const float* emb = (const float*)d_in[1];   // [1024, 64]
    float* out  = (float*)d_out;                // z_q (4194304) | loss (1) | indices (65536)
    float* loss = out + 4194304;
    float* idxf = out + 4194305;

    float* h_    = (float*)d_ws;                // [1024]
    float* hneg_ = h_ + KDIM;                   // [1024]
    __half* eh_  = (__half*)(hneg_ + KDIM);     // [1024*64] halves

    vq_prep_e<<<KDIM / 16, 256, 0, stream>>>(emb, h_, hneg_, eh_, loss);
    vq_mfma_kernel<<<NVEC / 64, 256, 0, stream>>>(z, emb, eh_, h_, hneg_, out, loss, idxf);
}